// Round 3
// baseline (233.078 us; speedup 1.0000x reference)
//
#include <hip/hip_runtime.h>
#include <hip/hip_bf16.h>
#include <cstddef>

// Problem constants (from reference)
#define QN 10000
#define DD 64
#define MM 50
#define BB 64
#define TT 512
#define WPAD 52    // padded w row stride in floats
#define CC 32      // chunks (compile-time -> full unroll)
#define LL 16      // steps per chunk = TT/CC
#define MH 25      // m's per half-wave split

__device__ __forceinline__ float rl(float v, int l) {
  return __uint_as_float(__builtin_amdgcn_readlane(__float_as_uint(v), l));
}

// ---------------------------------------------------------------------------
// K1 (fused): blocks [0,1024) compute w = softmax(k@Mk^T);
//             blocks [1024,2048) compute e = sigmoid(v@e_W+b), a = tanh(v@a_W+b).
// One wave per row-slice; weights in VGPRs; k/v rows wave-uniform.
// ---------------------------------------------------------------------------
__global__ __launch_bounds__(256) void k1_fused(
    const int* __restrict__ question, const int* __restrict__ response,
    const float* __restrict__ k_emb, const float* __restrict__ v_emb,
    const float* __restrict__ Mk,
    const float* __restrict__ e_W, const float* __restrict__ e_b,
    const float* __restrict__ a_W, const float* __restrict__ a_b,
    float* __restrict__ w_buf, float* __restrict__ e_buf, float* __restrict__ a_buf) {
  const int lane = threadIdx.x & 63;
  const int wslot = __builtin_amdgcn_readfirstlane((int)(threadIdx.x >> 6));

  if (blockIdx.x < 1024) {
    // ---- w path ----
    const int wid = blockIdx.x * 4 + wslot;            // 0..4095
    float mk[64];
    const int mrow = lane < MM ? lane : (MM - 1);
#pragma unroll
    for (int i = 0; i < 64; i += 4) {
      const float4 t4 = *(const float4*)(Mk + mrow * 64 + i);
      mk[i] = t4.x; mk[i + 1] = t4.y; mk[i + 2] = t4.z; mk[i + 3] = t4.w;
    }
    for (int row = wid; row < BB * TT; row += 4096) {
      const int q = question[row];                     // wave-uniform
      const float* __restrict__ krow = k_emb + (size_t)q * 64;
      float l0 = 0.f, l1 = 0.f, l2 = 0.f, l3 = 0.f;
#pragma unroll
      for (int i = 0; i < 64; i += 4) {
        const float4 kv = *(const float4*)(krow + i);
        l0 = fmaf(kv.x, mk[i], l0);
        l1 = fmaf(kv.y, mk[i + 1], l1);
        l2 = fmaf(kv.z, mk[i + 2], l2);
        l3 = fmaf(kv.w, mk[i + 3], l3);
      }
      const float lm = (l0 + l1) + (l2 + l3);
      float lv = (lane < MM) ? lm : -3.4e38f;
#pragma unroll
      for (int off = 32; off > 0; off >>= 1) lv = fmaxf(lv, __shfl_xor(lv, off));
      float pe = (lane < MM) ? __expf(lm - lv) : 0.f;
      float ss = pe;
#pragma unroll
      for (int off = 32; off > 0; off >>= 1) ss += __shfl_xor(ss, off);
      if (lane < MM) w_buf[(size_t)row * WPAD + lane] = pe / ss;
    }
  } else {
    // ---- e/a path ----
    const int wid = (blockIdx.x - 1024) * 4 + wslot;   // 0..4095
    float ew[64], aw[64];
#pragma unroll
    for (int i = 0; i < 64; ++i) {
      ew[i] = e_W[i * 64 + lane];
      aw[i] = a_W[i * 64 + lane];
    }
    const float eb = e_b[lane];
    const float ab = a_b[lane];
    for (int row = wid; row < BB * TT; row += 4096) {
      const int q = question[row];
      const int r = response[row];
      const float* __restrict__ vrow = v_emb + ((size_t)q + (size_t)QN * r) * 64;
      float e0 = eb, e1 = 0.f, a0 = ab, a1 = 0.f;
#pragma unroll
      for (int i = 0; i < 64; i += 2) {
        const float2 vv = *(const float2*)(vrow + i);
        e0 = fmaf(vv.x, ew[i], e0);
        a0 = fmaf(vv.x, aw[i], a0);
        e1 = fmaf(vv.y, ew[i + 1], e1);
        a1 = fmaf(vv.y, aw[i + 1], a1);
      }
      const float se = e0 + e1, sa = a0 + a1;
      e_buf[(size_t)row * 64 + lane] = 1.f / (1.f + __expf(-se));
      const float t2 = __expf(2.f * sa);
      a_buf[(size_t)row * 64 + lane] = 1.f - 2.f / (t2 + 1.f);   // tanh
    }
  }
}

// ---------------------------------------------------------------------------
// kA: composed affine (A,B) per (m,d) for each (b,chunk). Two waves per unit
// (25 m's each); lane = d; fully unrolled LL=16 steps; w broadcast via
// coalesced lane load + v_readlane. No barriers, no LDS.
// ---------------------------------------------------------------------------
__global__ __launch_bounds__(256) void kA_chunk(
    const float* __restrict__ w_buf, const float* __restrict__ e_buf,
    const float* __restrict__ a_buf, const float* __restrict__ mask,
    float* __restrict__ A_arr, float* __restrict__ B_arr) {
  const int lane = threadIdx.x & 63;
  const int wslot = __builtin_amdgcn_readfirstlane((int)(threadIdx.x >> 6));
  const int gid = blockIdx.x * 4 + wslot;              // 0..4095
  const int unit = gid >> 1;                           // b*CC + c
  const int m0 = (gid & 1) * MH;
  const int b = unit >> 5;                             // CC = 32
  const int c = unit & 31;

  float Am[MH], Bm[MH];
#pragma unroll
  for (int m = 0; m < MH; ++m) { Am[m] = 1.f; Bm[m] = 0.f; }

  const size_t row0 = (size_t)b * TT + c * LL;
#pragma unroll
  for (int j = 0; j < LL; ++j) {
    const size_t row = row0 + j;
    const float wv = w_buf[row * WPAD + lane];         // coalesced lane load
    const float ed = e_buf[row * 64 + lane];
    const float ad = a_buf[row * 64 + lane];
    const float mv = mask[row];
    if (mv == 1.0f) {
#pragma unroll
      for (int m = 0; m < MH; ++m) {
        const float wm = rl(wv, m0 + m);               // wave-uniform scalar
        const float al = fmaf(-wm, ed, 1.0f);
        Am[m] *= al;
        Bm[m] = fmaf(Bm[m], al, wm * ad);
      }
    }
  }
  float* __restrict__ Ad = A_arr + (size_t)unit * (MM * 64);
  float* __restrict__ Bd = B_arr + (size_t)unit * (MM * 64);
#pragma unroll
  for (int m = 0; m < MH; ++m) {
    Ad[(m0 + m) * 64 + lane] = Am[m];
    Bd[(m0 + m) * 64 + lane] = Bm[m];
  }
}

// ---------------------------------------------------------------------------
// kB: chunk-entry states. Parallel over B*M*D = 204,800 elements; fully
// unrolled CC=32 chain with all 64 A/B loads issued up front.
// ---------------------------------------------------------------------------
__global__ __launch_bounds__(256) void kB_entry(
    const float* __restrict__ A_arr, const float* __restrict__ B_arr,
    const float* __restrict__ Mv0, float* __restrict__ entry) {
  const int idx = blockIdx.x * 256 + (int)threadIdx.x; // < 204800
  const int b = idx / (MM * 64);
  const int r = idx - b * (MM * 64);
  const size_t base = (size_t)b * CC * (MM * 64) + r;

  float Ac[CC], Bc[CC];
#pragma unroll
  for (int c = 0; c < CC; ++c) {
    Ac[c] = A_arr[base + (size_t)c * (MM * 64)];
    Bc[c] = B_arr[base + (size_t)c * (MM * 64)];
  }
  float s = Mv0[r];
#pragma unroll
  for (int c = 0; c < CC; ++c) {
    entry[base + (size_t)c * (MM * 64)] = s;
    s = fmaf(Ac[c], s, Bc[c]);
  }
}

// ---------------------------------------------------------------------------
// kC: replay each chunk from its entry state, emitting partial reads
// (half h sums its 25 m's). Two waves per unit; fully unrolled; no barriers.
// ---------------------------------------------------------------------------
__global__ __launch_bounds__(256) void kC_read(
    const float* __restrict__ w_buf, const float* __restrict__ e_buf,
    const float* __restrict__ a_buf, const float* __restrict__ mask,
    const float* __restrict__ entry, float* __restrict__ read_part,
    size_t rN) {
  const int lane = threadIdx.x & 63;
  const int wslot = __builtin_amdgcn_readfirstlane((int)(threadIdx.x >> 6));
  const int gid = blockIdx.x * 4 + wslot;              // 0..4095
  const int unit = gid >> 1;                           // b*CC + c
  const int half = gid & 1;
  const int m0 = half * MH;
  const int b = unit >> 5;
  const int c = unit & 31;

  float s[MH];
  const float* __restrict__ ep = entry + (size_t)unit * (MM * 64);
#pragma unroll
  for (int m = 0; m < MH; ++m) s[m] = ep[(m0 + m) * 64 + lane];

  float* __restrict__ rp = read_part + half * rN;
#pragma unroll
  for (int j = 0; j < LL; ++j) {
    const int t = c * LL + j;
    const size_t row = (size_t)b * TT + t;
    const float wv = w_buf[row * WPAD + lane];
    const float ed = e_buf[row * 64 + lane];
    const float ad = a_buf[row * 64 + lane];
    const float mv = mask[row];

    if (t >= 1) {                                      // uniform branch
      float a0 = 0.f, a1 = 0.f;
#pragma unroll
      for (int m = 0; m < MH; m += 2) {
        a0 = fmaf(rl(wv, m0 + m), s[m], a0);
        if (m + 1 < MH) a1 = fmaf(rl(wv, m0 + m + 1), s[m + 1], a1);
      }
      rp[((size_t)b * (TT - 1) + (t - 1)) * 64 + lane] = a0 + a1;
    }
    if (mv == 1.0f) {
#pragma unroll
      for (int m = 0; m < MH; ++m) {
        const float wm = rl(wv, m0 + m);
        s[m] = fmaf(wm, fmaf(-s[m], ed, ad), s[m]);
      }
    }
  }
}

// ---------------------------------------------------------------------------
// k3: f = tanh([read | k_{t+1}] @ f_W + f_b); p = f @ p_W + p_b.
// read = sum of the two partial halves from kC.
// ---------------------------------------------------------------------------
__global__ __launch_bounds__(256) void k3_out(
    const int* __restrict__ question, const float* __restrict__ k_emb,
    const float* __restrict__ read_part, size_t rN,
    const float* __restrict__ f_W, const float* __restrict__ f_b,
    const float* __restrict__ p_W, const float* __restrict__ p_b,
    float* __restrict__ out) {
  const int lane = threadIdx.x & 63;
  const int wslot = __builtin_amdgcn_readfirstlane((int)(threadIdx.x >> 6));
  const int wid = blockIdx.x * 4 + wslot;              // 0..4095

  float fw[128];
#pragma unroll
  for (int i = 0; i < 128; ++i) fw[i] = f_W[i * 64 + lane];
  const float fb = f_b[lane];
  const float pw = p_W[lane];
  const float pb = p_b[0];

  for (int row = wid; row < BB * (TT - 1); row += 4096) {
    const int b = row / (TT - 1);
    const int tp = row - b * (TT - 1);
    const float* __restrict__ r0 = read_part + (size_t)row * 64;
    const float* __restrict__ r1 = r0 + rN;
    const int qn = question[b * TT + tp + 1];          // wave-uniform
    const float* __restrict__ krow = k_emb + (size_t)qn * 64;

    float f0 = fb, f1 = 0.f, f2 = 0.f, f3 = 0.f;
#pragma unroll
    for (int i = 0; i < 64; i += 4) {
      const float4 u = *(const float4*)(r0 + i);
      const float4 v = *(const float4*)(r1 + i);
      f0 = fmaf(u.x + v.x, fw[i], f0);
      f1 = fmaf(u.y + v.y, fw[i + 1], f1);
      f2 = fmaf(u.z + v.z, fw[i + 2], f2);
      f3 = fmaf(u.w + v.w, fw[i + 3], f3);
    }
#pragma unroll
    for (int i = 0; i < 64; i += 4) {
      const float4 kv = *(const float4*)(krow + i);
      f0 = fmaf(kv.x, fw[64 + i], f0);
      f1 = fmaf(kv.y, fw[64 + i + 1], f1);
      f2 = fmaf(kv.z, fw[64 + i + 2], f2);
      f3 = fmaf(kv.w, fw[64 + i + 3], f3);
    }
    const float f = (f0 + f1) + (f2 + f3);
    const float t2 = __expf(2.f * f);
    const float fv = 1.f - 2.f / (t2 + 1.f);           // tanh

    float acc = fv * pw;
#pragma unroll
    for (int off = 32; off > 0; off >>= 1) acc += __shfl_xor(acc, off);
    if (lane == 0) out[row] = acc + pb;
  }
}

// ---------------------------------------------------------------------------
extern "C" void kernel_launch(void* const* d_in, const int* in_sizes, int n_in,
                              void* d_out, int out_size, void* d_ws, size_t ws_size,
                              hipStream_t stream) {
  const int*   question = (const int*)d_in[0];
  const int*   response = (const int*)d_in[1];
  const float* mask     = (const float*)d_in[2];
  const float* k_emb    = (const float*)d_in[3];
  const float* v_emb    = (const float*)d_in[4];
  const float* Mk       = (const float*)d_in[5];
  const float* Mv0      = (const float*)d_in[6];
  const float* e_W      = (const float*)d_in[7];
  const float* e_b      = (const float*)d_in[8];
  const float* a_W      = (const float*)d_in[9];
  const float* a_b      = (const float*)d_in[10];
  const float* f_W      = (const float*)d_in[11];
  const float* f_b      = (const float*)d_in[12];
  const float* p_W      = (const float*)d_in[13];
  const float* p_b      = (const float*)d_in[14];
  float* out = (float*)d_out;

  // workspace layout (floats)
  const size_t wN = (size_t)BB * TT * WPAD;       // 1,703,936
  const size_t eN = (size_t)BB * TT * 64;         // 2,097,152
  const size_t rN = (size_t)BB * (TT - 1) * 64;   // 2,093,056
  const size_t abN = (size_t)BB * CC * MM * 64;   // 6,553,600
  float* ws = (float*)d_ws;
  float* w_buf     = ws;
  float* e_buf     = w_buf + wN;
  float* a_buf     = e_buf + eN;
  float* read_part = a_buf + eN;                  // 2 * rN
  float* A_arr     = read_part + 2 * rN;
  float* B_arr     = A_arr + abN;
  float* entry     = B_arr + abN;
  // total = 29,745,152 floats = 119 MB (< ws_size)

  hipLaunchKernelGGL(k1_fused, dim3(2048), dim3(256), 0, stream,
                     question, response, k_emb, v_emb, Mk, e_W, e_b, a_W, a_b,
                     w_buf, e_buf, a_buf);
  hipLaunchKernelGGL(kA_chunk, dim3(1024), dim3(256), 0, stream,
                     w_buf, e_buf, a_buf, mask, A_arr, B_arr);
  hipLaunchKernelGGL(kB_entry, dim3((BB * MM * 64) / 256), dim3(256), 0, stream,
                     A_arr, B_arr, Mv0, entry);
  hipLaunchKernelGGL(kC_read, dim3(1024), dim3(256), 0, stream,
                     w_buf, e_buf, a_buf, mask, entry, read_part, rN);
  hipLaunchKernelGGL(k3_out, dim3(1024), dim3(256), 0, stream,
                     question, k_emb, read_part, rN, f_W, f_b, p_W, p_b, out);
}